// Round 1
// baseline (446.763 us; speedup 1.0000x reference)
//
#include <hip/hip_runtime.h>
#include <math.h>

#define N 8000
#define D 256
#define P 128

// ---------------------------------------------------------------------------
// K1: dinv[row] = rsqrt(sum of adj row). One block per row, 256 threads.
// ---------------------------------------------------------------------------
__global__ __launch_bounds__(256) void deg_kernel(const float* __restrict__ adj,
                                                  float* __restrict__ dinv) {
    int row = blockIdx.x;
    const float4* r = (const float4*)(adj + (size_t)row * N);
    float s = 0.f;
    for (int i = threadIdx.x; i < N / 4; i += 256) {
        float4 a = r[i];
        s += a.x + a.y + a.z + a.w;
    }
    for (int off = 32; off > 0; off >>= 1) s += __shfl_down(s, off, 64);
    __shared__ float red[4];
    int lane = threadIdx.x & 63, wave = threadIdx.x >> 6;
    if (lane == 0) red[wave] = s;
    __syncthreads();
    if (threadIdx.x == 0) {
        float t = red[0] + red[1] + red[2] + red[3];
        dinv[row] = rsqrtf(t);   // deg >= 1 (self loops), safe
    }
}

// ---------------------------------------------------------------------------
// K2: projT[d][p] = b_att[d] + sum_k emb[pos[p]][k] * w_att[d][k]
//     pe2[p]     = sum_d emb[pos[p]][d] * w_weight[D + d]
// One block per p, 256 threads (thread d computes proj[p][d]).
// ---------------------------------------------------------------------------
__global__ __launch_bounds__(256) void proj_kernel(const float* __restrict__ emb,
                                                   const float* __restrict__ w_att,
                                                   const float* __restrict__ b_att,
                                                   const float* __restrict__ w_weight,
                                                   const int* __restrict__ pos_idx,
                                                   float* __restrict__ projT,
                                                   float* __restrict__ pe2) {
    int p = blockIdx.x;
    int row = pos_idx[p];
    __shared__ float e[D];
    __shared__ float red[D];
    int tid = threadIdx.x;
    e[tid] = emb[(size_t)row * D + tid];
    __syncthreads();
    float acc = b_att[tid];
    const float* wrow = w_att + (size_t)tid * D;
    #pragma unroll 4
    for (int k = 0; k < D; k++) acc += e[k] * wrow[k];
    projT[(size_t)tid * P + p] = acc;
    red[tid] = e[tid] * w_weight[D + tid];
    __syncthreads();
    for (int s = 128; s > 0; s >>= 1) {
        if (tid < s) red[tid] += red[tid + s];
        __syncthreads();
    }
    if (tid == 0) pe2[p] = red[0];
}

// ---------------------------------------------------------------------------
// K3: fused scores GEMM + mask + column softmax + mutual_w.
// Block = 256 threads handles 64 nodes x all 128 positives.
//   S[n][p] = adj[pos[p]][n] * dot(emb[n], proj[p])
//   probs = softmax over p;  mutual_w[n] = sigmoid(emb[n].w1 + sum_p probs*pe2[p])
// Register-tiled GEMM: thread (tx,ty) owns 4n x 8p, K-chunks of 32.
// ---------------------------------------------------------------------------
__global__ __launch_bounds__(256) void attn_kernel(const float* __restrict__ emb,
                                                   const float* __restrict__ projT,
                                                   const float* __restrict__ adj,
                                                   const int* __restrict__ pos_idx,
                                                   const float* __restrict__ pe2,
                                                   const float* __restrict__ w_weight,
                                                   float* __restrict__ mutual_w) {
    __shared__ float At[32][68];    // At[dk][nn] = emb[n0+nn][d0+dk]; pad 68 for b128 align + bank spread
    __shared__ float B[32][128];    // B[dk][p]   = projT[d0+dk][p]
    __shared__ float S[64][129];    // masked scores, pad 129 (2-way max on row access = free)
    __shared__ int   posrow[P];
    __shared__ float pe2s[P];
    __shared__ float w1[D];

    int tid = threadIdx.x;
    int tx = tid & 15;    // n-group: n = n0 + tx*4 + i
    int ty = tid >> 4;    // p-group: p = ty*8 + j
    int n0 = blockIdx.x * 64;

    if (tid < P) { posrow[tid] = pos_idx[tid]; pe2s[tid] = pe2[tid]; }
    w1[tid] = w_weight[tid];

    float acc[4][8];
    #pragma unroll
    for (int i = 0; i < 4; i++)
        #pragma unroll
        for (int j = 0; j < 8; j++) acc[i][j] = 0.f;

    for (int d0 = 0; d0 < D; d0 += 32) {
        __syncthreads();   // also covers the initial posrow/w1 stores
        // stage A chunk transposed: 2048 floats, 8 per thread
        {
            int nn = tid >> 2;
            int dk0 = (tid & 3) * 8;
            const float* src = emb + (size_t)(n0 + nn) * D + d0 + dk0;
            float4 v0 = *(const float4*)(src);
            float4 v1 = *(const float4*)(src + 4);
            At[dk0 + 0][nn] = v0.x; At[dk0 + 1][nn] = v0.y;
            At[dk0 + 2][nn] = v0.z; At[dk0 + 3][nn] = v0.w;
            At[dk0 + 4][nn] = v1.x; At[dk0 + 5][nn] = v1.y;
            At[dk0 + 6][nn] = v1.z; At[dk0 + 7][nn] = v1.w;
        }
        // stage B chunk: 4096 floats, 4 x float4 per thread, layout-preserving
        #pragma unroll
        for (int r = 0; r < 4; r++) {
            int f = (r * 256 + tid) * 4;
            int dk = f >> 7, pp = f & 127;
            *(float4*)&B[dk][pp] = *(const float4*)(projT + (size_t)(d0 + dk) * P + pp);
        }
        __syncthreads();
        #pragma unroll
        for (int dk = 0; dk < 32; dk++) {
            float4 a4 = *(const float4*)&At[dk][tx * 4];
            float b[8];
            *(float4*)&b[0] = *(const float4*)&B[dk][ty * 8];
            *(float4*)&b[4] = *(const float4*)&B[dk][ty * 8 + 4];
            #pragma unroll
            for (int j = 0; j < 8; j++) {
                acc[0][j] += a4.x * b[j];
                acc[1][j] += a4.y * b[j];
                acc[2][j] += a4.z * b[j];
                acc[3][j] += a4.w * b[j];
            }
        }
    }
    // mask with gathered adjacency rows, write scores to LDS
    #pragma unroll
    for (int j = 0; j < 8; j++) {
        int p = ty * 8 + j;
        float4 m4 = *(const float4*)(adj + (size_t)posrow[p] * N + n0 + tx * 4);
        S[tx * 4 + 0][p] = acc[0][j] * m4.x;
        S[tx * 4 + 1][p] = acc[1][j] * m4.y;
        S[tx * 4 + 2][p] = acc[2][j] * m4.z;
        S[tx * 4 + 3][p] = acc[3][j] * m4.w;
    }
    __syncthreads();
    // softmax over p + fold context into pe2 dot + e1 + sigmoid
    if (tid < 64) {
        int n = n0 + tid;
        float mm = -1e30f;
        for (int p = 0; p < P; p++) mm = fmaxf(mm, S[tid][p]);
        float Z = 0.f, ape = 0.f;
        for (int p = 0; p < P; p++) {
            float ex = __expf(S[tid][p] - mm);
            Z += ex;
            ape += ex * pe2s[p];
        }
        float e1 = 0.f;
        const float4* er = (const float4*)(emb + (size_t)n * D);
        #pragma unroll 4
        for (int d = 0; d < D / 4; d++) {
            float4 ev = er[d];
            e1 += ev.x * w1[4 * d] + ev.y * w1[4 * d + 1] +
                  ev.z * w1[4 * d + 2] + ev.w * w1[4 * d + 3];
        }
        float logit = e1 + ape / Z;
        mutual_w[n] = 1.f / (1.f + __expf(-logit));
    }
}

// ---------------------------------------------------------------------------
// K4: v[n] = dinv[n] * mutual_w[n] * sum_{p unique} adj[pos[p]][n] * dinv[pos[p]]
// (one-hot `inputs` dedupes pos_idx; it's sorted so adjacent-compare works)
// ---------------------------------------------------------------------------
__global__ __launch_bounds__(256) void out1_kernel(const float* __restrict__ adj,
                                                   const int* __restrict__ pos_idx,
                                                   const float* __restrict__ dinv,
                                                   const float* __restrict__ mutual_w,
                                                   float* __restrict__ v) {
    __shared__ int posrow[P];
    __shared__ float fac[P];
    int tid = threadIdx.x;
    if (tid < P) {
        int r = pos_idx[tid];
        posrow[tid] = r;
        float f = dinv[r];
        if (tid > 0 && pos_idx[tid - 1] == r) f = 0.f;  // dedupe
        fac[tid] = f;
    }
    __syncthreads();
    int n = blockIdx.x * 256 + tid;
    if (n < N) {
        float s = 0.f;
        #pragma unroll 4
        for (int p = 0; p < P; p++) s += adj[(size_t)posrow[p] * N + n] * fac[p];
        v[n] = s * dinv[n] * mutual_w[n];
    }
}

// ---------------------------------------------------------------------------
// K5: out[j] = w_final * dinv[j] * dot(adj row j, v)   (adj symmetric)
// ---------------------------------------------------------------------------
__global__ __launch_bounds__(256) void final_kernel(const float* __restrict__ adj,
                                                    const float* __restrict__ v,
                                                    const float* __restrict__ dinv,
                                                    const float* __restrict__ w_final,
                                                    float* __restrict__ out) {
    int row = blockIdx.x;
    const float4* r = (const float4*)(adj + (size_t)row * N);
    const float4* vv = (const float4*)v;
    float s = 0.f;
    for (int i = threadIdx.x; i < N / 4; i += 256) {
        float4 a = r[i];
        float4 b = vv[i];
        s += a.x * b.x + a.y * b.y + a.z * b.z + a.w * b.w;
    }
    for (int off = 32; off > 0; off >>= 1) s += __shfl_down(s, off, 64);
    __shared__ float red[4];
    int lane = threadIdx.x & 63, wave = threadIdx.x >> 6;
    if (lane == 0) red[wave] = s;
    __syncthreads();
    if (threadIdx.x == 0)
        out[row] = (red[0] + red[1] + red[2] + red[3]) * dinv[row] * w_final[0];
}

// ---------------------------------------------------------------------------
extern "C" void kernel_launch(void* const* d_in, const int* in_sizes, int n_in,
                              void* d_out, int out_size, void* d_ws, size_t ws_size,
                              hipStream_t stream) {
    const float* adj    = (const float*)d_in[0];
    const float* emb    = (const float*)d_in[1];
    const float* w_att  = (const float*)d_in[2];
    const float* b_att  = (const float*)d_in[3];
    const float* w_w    = (const float*)d_in[4];
    const float* w_f    = (const float*)d_in[5];
    const int*   pos    = (const int*)d_in[6];
    float* out = (float*)d_out;

    float* ws     = (float*)d_ws;
    float* dinv   = ws;                 // N
    float* projT  = dinv + N;           // D*P = 32768
    float* pe2    = projT + (size_t)D * P; // P
    float* mutual = pe2 + P;            // N
    float* v      = mutual + N;         // N

    deg_kernel  <<<N,              256, 0, stream>>>(adj, dinv);
    proj_kernel <<<P,              256, 0, stream>>>(emb, w_att, b_att, w_w, pos, projT, pe2);
    attn_kernel <<<N / 64,         256, 0, stream>>>(emb, projT, adj, pos, pe2, w_w, mutual);
    out1_kernel <<<(N + 255) / 256, 256, 0, stream>>>(adj, pos, dinv, mutual, v);
    final_kernel<<<N,              256, 0, stream>>>(adj, v, dinv, w_f, out);
}

// Round 2
// 407.170 us; speedup vs baseline: 1.0972x; 1.0972x over previous
//
#include <hip/hip_runtime.h>
#include <math.h>

#define N 8000
#define D 256
#define P 128
#define NW 250   // bitmask words per row = N/32

// ---------------------------------------------------------------------------
// K1: dinv[row] = rsqrt(rowsum(adj)); ALSO compress row into 250-word bitmask.
// One block per row; thread t (<250) owns word t = elements [32t, 32t+32).
// ---------------------------------------------------------------------------
__global__ __launch_bounds__(256) void deg_kernel(const float* __restrict__ adj,
                                                  float* __restrict__ dinv,
                                                  unsigned int* __restrict__ msk) {
    int row = blockIdx.x;
    int tid = threadIdx.x;
    const float4* r = (const float4*)(adj + (size_t)row * N);
    float s = 0.f;
    if (tid < NW) {
        unsigned int m = 0;
        #pragma unroll
        for (int j = 0; j < 8; j++) {
            float4 a = r[tid * 8 + j];
            s += a.x + a.y + a.z + a.w;
            m |= (a.x != 0.f ? 1u : 0u) << (4 * j + 0);
            m |= (a.y != 0.f ? 1u : 0u) << (4 * j + 1);
            m |= (a.z != 0.f ? 1u : 0u) << (4 * j + 2);
            m |= (a.w != 0.f ? 1u : 0u) << (4 * j + 3);
        }
        msk[(size_t)row * NW + tid] = m;
    }
    for (int off = 32; off > 0; off >>= 1) s += __shfl_down(s, off, 64);
    __shared__ float red[4];
    int lane = tid & 63, wave = tid >> 6;
    if (lane == 0) red[wave] = s;
    __syncthreads();
    if (tid == 0) dinv[row] = rsqrtf(red[0] + red[1] + red[2] + red[3]);
}

// ---------------------------------------------------------------------------
// K2: projT[d][p] = b_att[d] + sum_k emb[pos[p]][k] * w_att[d][k]
//     pe2[p]     = sum_d emb[pos[p]][d] * w_weight[D + d]
// ---------------------------------------------------------------------------
__global__ __launch_bounds__(256) void proj_kernel(const float* __restrict__ emb,
                                                   const float* __restrict__ w_att,
                                                   const float* __restrict__ b_att,
                                                   const float* __restrict__ w_weight,
                                                   const int* __restrict__ pos_idx,
                                                   float* __restrict__ projT,
                                                   float* __restrict__ pe2) {
    int p = blockIdx.x;
    int row = pos_idx[p];
    __shared__ float e[D];
    __shared__ float red[D];
    int tid = threadIdx.x;
    e[tid] = emb[(size_t)row * D + tid];
    __syncthreads();
    float acc = b_att[tid];
    const float* wrow = w_att + (size_t)tid * D;
    #pragma unroll 4
    for (int k = 0; k < D; k++) acc += e[k] * wrow[k];
    projT[(size_t)tid * P + p] = acc;
    red[tid] = e[tid] * w_weight[D + tid];
    __syncthreads();
    for (int s = 128; s > 0; s >>= 1) {
        if (tid < s) red[tid] += red[tid + s];
        __syncthreads();
    }
    if (tid == 0) pe2[p] = red[0];
}

// ---------------------------------------------------------------------------
// K3: fused scores GEMM + bitmask mask + column softmax + mutual_w + first
// propagation hop. Block = 256 threads handles 64 nodes x all 128 positives.
//   S[n][p]   = bit(pos[p],n) * dot(emb[n], proj[p])
//   probs     = softmax over p
//   mutual[n] = sigmoid(emb[n].w1 + sum_p probs[p,n]*pe2[p])
//   v[n]      = dinv[n] * mutual[n] * sum_{p unique} bit(pos[p],n)*dinv[pos[p]]
// ---------------------------------------------------------------------------
__global__ __launch_bounds__(256) void attn_kernel(const float* __restrict__ emb,
                                                   const float* __restrict__ projT,
                                                   const unsigned int* __restrict__ msk,
                                                   const int* __restrict__ pos_idx,
                                                   const float* __restrict__ pe2,
                                                   const float* __restrict__ w_weight,
                                                   const float* __restrict__ dinv,
                                                   float* __restrict__ v) {
    __shared__ float At[32][68];    // At[dk][nn] = emb[n0+nn][d0+dk]
    __shared__ float B[32][128];    // B[dk][p]   = projT[d0+dk][p]
    __shared__ float S[64][129];    // masked scores
    __shared__ float R[16][68];     // per-ty partial hop sums
    __shared__ int   posrow[P];
    __shared__ float pe2s[P];
    __shared__ float fac[P];        // deduped dinv[pos[p]]
    __shared__ float w1[D];

    int tid = threadIdx.x;
    int tx = tid & 15;    // n-group: n = n0 + tx*4 + i
    int ty = tid >> 4;    // p-group: p = ty*8 + j
    int n0 = blockIdx.x * 64;

    if (tid < P) {
        int r0 = pos_idx[tid];
        posrow[tid] = r0;
        pe2s[tid] = pe2[tid];
        float f = dinv[r0];
        if (tid > 0 && pos_idx[tid - 1] == r0) f = 0.f;  // dedupe (sorted idx)
        fac[tid] = f;
    }
    w1[tid] = w_weight[tid];

    float acc[4][8];
    #pragma unroll
    for (int i = 0; i < 4; i++)
        #pragma unroll
        for (int j = 0; j < 8; j++) acc[i][j] = 0.f;
    float e1 = 0.f;   // emb[n].w1, accumulated by threads tid<64

    for (int d0 = 0; d0 < D; d0 += 32) {
        __syncthreads();   // covers init stores on first iter, At/B reuse after
        {   // stage A chunk transposed: 2048 floats, 8 per thread
            int nn = tid >> 2;
            int dk0 = (tid & 3) * 8;
            const float* src = emb + (size_t)(n0 + nn) * D + d0 + dk0;
            float4 v0 = *(const float4*)(src);
            float4 v1 = *(const float4*)(src + 4);
            At[dk0 + 0][nn] = v0.x; At[dk0 + 1][nn] = v0.y;
            At[dk0 + 2][nn] = v0.z; At[dk0 + 3][nn] = v0.w;
            At[dk0 + 4][nn] = v1.x; At[dk0 + 5][nn] = v1.y;
            At[dk0 + 6][nn] = v1.z; At[dk0 + 7][nn] = v1.w;
        }
        #pragma unroll
        for (int r = 0; r < 4; r++) {   // stage B chunk: 4096 floats
            int f = (r * 256 + tid) * 4;
            int dk = f >> 7, pp = f & 127;
            *(float4*)&B[dk][pp] = *(const float4*)(projT + (size_t)(d0 + dk) * P + pp);
        }
        __syncthreads();
        #pragma unroll
        for (int dk = 0; dk < 32; dk++) {
            float4 a4 = *(const float4*)&At[dk][tx * 4];
            float b[8];
            *(float4*)&b[0] = *(const float4*)&B[dk][ty * 8];
            *(float4*)&b[4] = *(const float4*)&B[dk][ty * 8 + 4];
            #pragma unroll
            for (int j = 0; j < 8; j++) {
                acc[0][j] += a4.x * b[j];
                acc[1][j] += a4.y * b[j];
                acc[2][j] += a4.z * b[j];
                acc[3][j] += a4.w * b[j];
            }
        }
        if (tid < 64) {  // fold e1 = emb[n].w1 using the staged tile
            float t = 0.f;
            #pragma unroll
            for (int dk = 0; dk < 32; dk++) t += At[dk][tid] * w1[d0 + dk];
            e1 += t;
        }
    }

    // mask via bitmask + write scores + accumulate hop-1 partials
    float vp[4] = {0.f, 0.f, 0.f, 0.f};
    int wbase = (n0 + tx * 4) >> 5;       // word index within a row
    int bsh = (tx & 7) * 4;               // bit offset of this thread's 4 n's
    #pragma unroll
    for (int j = 0; j < 8; j++) {
        int p = ty * 8 + j;
        unsigned int w = msk[(size_t)posrow[p] * NW + wbase];
        float fp = fac[p];
        float m0 = (w >> (bsh + 0)) & 1u ? 1.f : 0.f;
        float m1 = (w >> (bsh + 1)) & 1u ? 1.f : 0.f;
        float m2 = (w >> (bsh + 2)) & 1u ? 1.f : 0.f;
        float m3 = (w >> (bsh + 3)) & 1u ? 1.f : 0.f;
        S[tx * 4 + 0][p] = acc[0][j] * m0;
        S[tx * 4 + 1][p] = acc[1][j] * m1;
        S[tx * 4 + 2][p] = acc[2][j] * m2;
        S[tx * 4 + 3][p] = acc[3][j] * m3;
        vp[0] += m0 * fp; vp[1] += m1 * fp;
        vp[2] += m2 * fp; vp[3] += m3 * fp;
    }
    #pragma unroll
    for (int i = 0; i < 4; i++) R[ty][tx * 4 + i] = vp[i];
    __syncthreads();

    if (tid < 64) {
        int n = n0 + tid;
        float mm = -1e30f;
        for (int p = 0; p < P; p++) mm = fmaxf(mm, S[tid][p]);
        float Z = 0.f, ape = 0.f;
        for (int p = 0; p < P; p++) {
            float ex = __expf(S[tid][p] - mm);
            Z += ex;
            ape += ex * pe2s[p];
        }
        float vs = 0.f;
        #pragma unroll
        for (int t = 0; t < 16; t++) vs += R[t][tid];
        float logit = e1 + ape / Z;
        float mw = 1.f / (1.f + __expf(-logit));
        v[n] = vs * dinv[n] * mw;
    }
}

// ---------------------------------------------------------------------------
// K4: out[j] = w_final * dinv[j] * sum_{n: bit(j,n)} v[n]   (adj symmetric)
// One wave per row (4 rows/block), sparse iteration over set bits.
// ---------------------------------------------------------------------------
__global__ __launch_bounds__(256) void final_kernel(const unsigned int* __restrict__ msk,
                                                    const float* __restrict__ vvec,
                                                    const float* __restrict__ dinv,
                                                    const float* __restrict__ w_final,
                                                    float* __restrict__ out) {
    int wave = threadIdx.x >> 6, lane = threadIdx.x & 63;
    int row = blockIdx.x * 4 + wave;
    const unsigned int* mrow = msk + (size_t)row * NW;
    float s = 0.f;
    for (int wi = lane; wi < NW; wi += 64) {
        unsigned int m = mrow[wi];
        int base = wi * 32;
        while (m) {
            int k = __ffs(m) - 1;
            s += vvec[base + k];
            m &= m - 1;
        }
    }
    for (int off = 32; off > 0; off >>= 1) s += __shfl_down(s, off, 64);
    if (lane == 0) out[row] = s * dinv[row] * w_final[0];
}

// ---------------------------------------------------------------------------
extern "C" void kernel_launch(void* const* d_in, const int* in_sizes, int n_in,
                              void* d_out, int out_size, void* d_ws, size_t ws_size,
                              hipStream_t stream) {
    const float* adj    = (const float*)d_in[0];
    const float* emb    = (const float*)d_in[1];
    const float* w_att  = (const float*)d_in[2];
    const float* b_att  = (const float*)d_in[3];
    const float* w_w    = (const float*)d_in[4];
    const float* w_f    = (const float*)d_in[5];
    const int*   pos    = (const int*)d_in[6];
    float* out = (float*)d_out;

    float* ws     = (float*)d_ws;
    float* dinv   = ws;                       // N
    float* projT  = dinv + N;                 // D*P
    float* pe2    = projT + (size_t)D * P;    // P
    float* v      = pe2 + P;                  // N
    unsigned int* msk = (unsigned int*)(v + N);  // 8000*250 words = 8 MB

    deg_kernel  <<<N,      256, 0, stream>>>(adj, dinv, msk);
    proj_kernel <<<P,      256, 0, stream>>>(emb, w_att, b_att, w_w, pos, projT, pe2);
    attn_kernel <<<N / 64, 256, 0, stream>>>(emb, projT, msk, pos, pe2, w_w, dinv, v);
    final_kernel<<<N / 4,  256, 0, stream>>>(msk, v, dinv, w_f, out);
}

// Round 3
// 402.413 us; speedup vs baseline: 1.1102x; 1.0118x over previous
//
#include <hip/hip_runtime.h>
#include <math.h>

#define N 8000
#define D 256
#define P 128
#define NW 250   // bitmask words per row = N/32

// ---------------------------------------------------------------------------
// K1 (fused): blocks [0,8000): dinv[row] = rsqrt(rowsum(adj)) + row bitmask.
//             blocks [8000,8128): proj for positive p = blockIdx-8000:
//               projT[d][p] = b_att[d] + sum_k emb[pos[p]][k]*w_att[d][k]
//               pe2[p]      = sum_d emb[pos[p]][d]*w_weight[D+d]
// Independent work — proj blocks hide inside deg's BW-bound window.
// ---------------------------------------------------------------------------
__global__ __launch_bounds__(256) void prep_kernel(const float* __restrict__ adj,
                                                   const float* __restrict__ emb,
                                                   const float* __restrict__ w_att,
                                                   const float* __restrict__ b_att,
                                                   const float* __restrict__ w_weight,
                                                   const int* __restrict__ pos_idx,
                                                   float* __restrict__ dinv,
                                                   unsigned int* __restrict__ msk,
                                                   float* __restrict__ projT,
                                                   float* __restrict__ pe2) {
    int tid = threadIdx.x;
    if (blockIdx.x < N) {
        // ---- degree + bitmask path ----
        int row = blockIdx.x;
        const float4* r = (const float4*)(adj + (size_t)row * N);
        float s = 0.f;
        if (tid < NW) {
            unsigned int m = 0;
            #pragma unroll
            for (int j = 0; j < 8; j++) {
                float4 a = r[tid * 8 + j];
                s += a.x + a.y + a.z + a.w;
                m |= (a.x != 0.f ? 1u : 0u) << (4 * j + 0);
                m |= (a.y != 0.f ? 1u : 0u) << (4 * j + 1);
                m |= (a.z != 0.f ? 1u : 0u) << (4 * j + 2);
                m |= (a.w != 0.f ? 1u : 0u) << (4 * j + 3);
            }
            msk[(size_t)row * NW + tid] = m;
        }
        for (int off = 32; off > 0; off >>= 1) s += __shfl_down(s, off, 64);
        __shared__ float red4[4];
        int lane = tid & 63, wave = tid >> 6;
        if (lane == 0) red4[wave] = s;
        __syncthreads();
        if (tid == 0) dinv[row] = rsqrtf(red4[0] + red4[1] + red4[2] + red4[3]);
    } else {
        // ---- projection path ----
        int p = blockIdx.x - N;
        int row = pos_idx[p];
        __shared__ float e[D];
        __shared__ float red[D];
        e[tid] = emb[(size_t)row * D + tid];
        __syncthreads();
        float acc = b_att[tid];
        const float* wrow = w_att + (size_t)tid * D;
        #pragma unroll 4
        for (int k = 0; k < D; k++) acc += e[k] * wrow[k];
        projT[(size_t)tid * P + p] = acc;
        red[tid] = e[tid] * w_weight[D + tid];
        __syncthreads();
        for (int s = 128; s > 0; s >>= 1) {
            if (tid < s) red[tid] += red[tid + s];
            __syncthreads();
        }
        if (tid == 0) pe2[p] = red[0];
    }
}

// ---------------------------------------------------------------------------
// K2: fused scores GEMM + bitmask mask + column softmax + mutual_w + hop 1.
// 250 blocks x 256 threads; block owns 32 nodes x all 128 positives.
// Thread (tx,ty) = (tid&7, tid>>3) owns 4n x 4p; K chunks of 32.
//   S[n][p]   = bit(pos[p],n) * dot(emb[n], proj[p])
//   mutual[n] = sigmoid(emb[n].w1 + sum_p softmax_p(S)[p,n]*pe2[p])
//   v[n]      = dinv[n]*mutual[n]*sum_{p uniq} bit(pos[p],n)*dinv[pos[p]]
// 32 aligned rows => each p needs exactly ONE mask word (staged in LDS).
// ---------------------------------------------------------------------------
__global__ __launch_bounds__(256) void attn_kernel(const float* __restrict__ emb,
                                                   const float* __restrict__ projT,
                                                   const unsigned int* __restrict__ msk,
                                                   const int* __restrict__ pos_idx,
                                                   const float* __restrict__ pe2,
                                                   const float* __restrict__ w_weight,
                                                   const float* __restrict__ dinv,
                                                   float* __restrict__ v) {
    __shared__ float At[32][36];        // At[dk][nn] = emb[n0+nn][d0+dk], +4 pad
    __shared__ float B[32][128];        // B[dk][p]   = projT[d0+dk][p]
    __shared__ float S[32][129];        // masked scores, padded
    __shared__ unsigned int mword[P];   // mask word per p for this 32-row stripe
    __shared__ int   posrow[P];
    __shared__ float pe2s[P];
    __shared__ float fac[P];            // deduped dinv[pos[p]]
    __shared__ float w1[D];

    int tid = threadIdx.x;
    int tx = tid & 7;     // n-group: n = n0 + tx*4 + i
    int ty = tid >> 3;    // p-group: p = ty*4 + j
    int n0 = blockIdx.x * 32;
    int wb = n0 >> 5;     // the single mask word index for this stripe

    if (tid < P) {
        int r0 = pos_idx[tid];
        posrow[tid] = r0;
        pe2s[tid] = pe2[tid];
        float f = dinv[r0];
        if (tid > 0 && pos_idx[tid - 1] == r0) f = 0.f;  // dedupe (sorted idx)
        fac[tid] = f;
    }
    w1[tid] = w_weight[tid];

    float acc[4][4];
    #pragma unroll
    for (int i = 0; i < 4; i++)
        #pragma unroll
        for (int j = 0; j < 4; j++) acc[i][j] = 0.f;
    float e1 = 0.f;   // emb[n].w1 for n = n0 + tid (threads tid<32)

    for (int d0 = 0; d0 < D; d0 += 32) {
        __syncthreads();   // covers init stores on first iter, tile reuse after
        {   // stage A chunk transposed: 1024 floats, 4 per thread
            int nn = tid >> 3;
            int dk0 = (tid & 7) * 4;
            float4 v0 = *(const float4*)(emb + (size_t)(n0 + nn) * D + d0 + dk0);
            At[dk0 + 0][nn] = v0.x; At[dk0 + 1][nn] = v0.y;
            At[dk0 + 2][nn] = v0.z; At[dk0 + 3][nn] = v0.w;
        }
        #pragma unroll
        for (int r = 0; r < 4; r++) {   // stage B chunk: 4096 floats
            int f = (r * 256 + tid) * 4;
            int dk = f >> 7, pp = f & 127;
            *(float4*)&B[dk][pp] = *(const float4*)(projT + (size_t)(d0 + dk) * P + pp);
        }
        __syncthreads();
        #pragma unroll
        for (int dk = 0; dk < 32; dk++) {
            float4 a4 = *(const float4*)&At[dk][tx * 4];
            float4 b4 = *(const float4*)&B[dk][ty * 4];
            acc[0][0] += a4.x * b4.x; acc[0][1] += a4.x * b4.y;
            acc[0][2] += a4.x * b4.z; acc[0][3] += a4.x * b4.w;
            acc[1][0] += a4.y * b4.x; acc[1][1] += a4.y * b4.y;
            acc[1][2] += a4.y * b4.z; acc[1][3] += a4.y * b4.w;
            acc[2][0] += a4.z * b4.x; acc[2][1] += a4.z * b4.y;
            acc[2][2] += a4.z * b4.z; acc[2][3] += a4.z * b4.w;
            acc[3][0] += a4.w * b4.x; acc[3][1] += a4.w * b4.y;
            acc[3][2] += a4.w * b4.z; acc[3][3] += a4.w * b4.w;
        }
        if (tid < 32) {  // fold e1 = emb[n].w1 using the staged tile
            float t = 0.f;
            #pragma unroll
            for (int dk = 0; dk < 32; dk++) t += At[dk][tid] * w1[d0 + dk];
            e1 += t;
        }
    }

    // stage the one mask word per p (posrow visible via loop syncs)
    if (tid < P) mword[tid] = msk[(size_t)posrow[tid] * NW + wb];
    __syncthreads();

    // mask + write scores
    #pragma unroll
    for (int j = 0; j < 4; j++) {
        int p = ty * 4 + j;
        unsigned int w = mword[p];
        #pragma unroll
        for (int i = 0; i < 4; i++) {
            int nn = tx * 4 + i;
            S[nn][p] = ((w >> nn) & 1u) ? acc[i][j] : 0.f;
        }
    }
    __syncthreads();

    // softmax over p + context-fold + hop-1 + sigmoid + v write
    if (tid < 32) {
        int n = n0 + tid;
        float mm = -1e30f;
        for (int p = 0; p < P; p++) mm = fmaxf(mm, S[tid][p]);
        float Z = 0.f, ape = 0.f, vs = 0.f;
        for (int p = 0; p < P; p++) {
            float ex = __expf(S[tid][p] - mm);
            Z += ex;
            ape += ex * pe2s[p];
            if ((mword[p] >> tid) & 1u) vs += fac[p];
        }
        float logit = e1 + ape / Z;
        float mw = 1.f / (1.f + __expf(-logit));
        v[n] = vs * dinv[n] * mw;
    }
}

// ---------------------------------------------------------------------------
// K3: out[j] = w_final * dinv[j] * sum_{n: bit(j,n)} v[n]   (adj symmetric)
// One wave per row (4 rows/block), sparse iteration over set bits.
// ---------------------------------------------------------------------------
__global__ __launch_bounds__(256) void final_kernel(const unsigned int* __restrict__ msk,
                                                    const float* __restrict__ vvec,
                                                    const float* __restrict__ dinv,
                                                    const float* __restrict__ w_final,
                                                    float* __restrict__ out) {
    int wave = threadIdx.x >> 6, lane = threadIdx.x & 63;
    int row = blockIdx.x * 4 + wave;
    const unsigned int* mrow = msk + (size_t)row * NW;
    float s = 0.f;
    for (int wi = lane; wi < NW; wi += 64) {
        unsigned int m = mrow[wi];
        int base = wi * 32;
        while (m) {
            int k = __ffs(m) - 1;
            s += vvec[base + k];
            m &= m - 1;
        }
    }
    for (int off = 32; off > 0; off >>= 1) s += __shfl_down(s, off, 64);
    if (lane == 0) out[row] = s * dinv[row] * w_final[0];
}

// ---------------------------------------------------------------------------
extern "C" void kernel_launch(void* const* d_in, const int* in_sizes, int n_in,
                              void* d_out, int out_size, void* d_ws, size_t ws_size,
                              hipStream_t stream) {
    const float* adj    = (const float*)d_in[0];
    const float* emb    = (const float*)d_in[1];
    const float* w_att  = (const float*)d_in[2];
    const float* b_att  = (const float*)d_in[3];
    const float* w_w    = (const float*)d_in[4];
    const float* w_f    = (const float*)d_in[5];
    const int*   pos    = (const int*)d_in[6];
    float* out = (float*)d_out;

    float* ws     = (float*)d_ws;
    float* dinv   = ws;                       // N
    float* projT  = dinv + N;                 // D*P
    float* pe2    = projT + (size_t)D * P;    // P
    float* v      = pe2 + P;                  // N
    unsigned int* msk = (unsigned int*)(v + N);  // 8000*250 words = 8 MB

    prep_kernel <<<N + P,  256, 0, stream>>>(adj, emb, w_att, b_att, w_w, pos,
                                             dinv, msk, projT, pe2);
    attn_kernel <<<N / 32, 256, 0, stream>>>(emb, projT, msk, pos, pe2, w_w, dinv, v);
    final_kernel<<<N / 4,  256, 0, stream>>>(msk, v, dinv, w_f, out);
}